// Round 8
// baseline (503.805 us; speedup 1.0000x reference)
//
#include <hip/hip_runtime.h>

#define N_NODES 50000
#define W_IN    256
#define W_OUT   256
#define HEADS   8
#define NUM_T   3
#define N_EDGES 800000
#define NEG_SLOPE 0.2f

#define NB      128           // coarse buckets (98 used)
#define BSH     9             // bucket = dst >> 9  (512 nodes/bucket)
#define BNODES  512
#define P1_EPT  16            // edges per thread in partition kernels
#define P1_CHUNK (256 * P1_EPT)   // 4096 edges per block
#define P1_BLOCKS ((N_EDGES + P1_CHUNK - 1) / P1_CHUNK)  // 196
#define NB_USED ((N_NODES + BNODES - 1) / BNODES)        // 98

#define MT_BLOCKS ((N_NODES + 127) / 128)   // 391 M-tiles
#define GATHER_BLOCKS ((N_NODES + 3) / 4)   // 12500
#define SPLIT_BLOCKS 25000                  // 3125 * 8: (node/16) x {xcd}

#if defined(__has_builtin)
#if __has_builtin(__builtin_amdgcn_global_load_lds)
#define HAS_GLL 1
#endif
#endif

typedef __attribute__((ext_vector_type(8))) short bf16x8;
typedef __attribute__((ext_vector_type(4))) float f32x4;

__device__ __forceinline__ unsigned short f2b(float f) {
    unsigned u = __float_as_uint(f);
    u = (u + 0x7fffu + ((u >> 16) & 1u)) >> 16;
    return (unsigned short)u;
}
__device__ __forceinline__ float blo(unsigned u) { return __uint_as_float(u << 16); }
__device__ __forceinline__ float bhi(unsigned u) { return __uint_as_float(u & 0xffff0000u); }

// ---------------------------------------------------------------------------
// x fp32 -> bf16 (RNE). 12500 blocks * 256 threads * 4 elems = 12.8M exact.
// ---------------------------------------------------------------------------
__global__ __launch_bounds__(256) void convert_x(const float* __restrict__ x,
                                                 unsigned short* __restrict__ xb) {
    const size_t i = ((size_t)blockIdx.x * 256 + threadIdx.x) * 4;
    const float4 v = *(const float4*)(x + i);
    ushort4 o;
    o.x = f2b(v.x); o.y = f2b(v.y); o.z = f2b(v.z); o.w = f2b(v.w);
    *(ushort4*)(xb + i) = o;
}

// ---------------------------------------------------------------------------
// W fp32 [t][k][n] -> bf16 transposed [t][n][k].
// ---------------------------------------------------------------------------
__global__ __launch_bounds__(256) void convert_W(const float* __restrict__ Wsrc,
                                                 unsigned short* __restrict__ Wt) {
    const int t = blockIdx.y;
    const int gid = blockIdx.x * 256 + threadIdx.x;  // 0..65535
    const int k = gid >> 8, n = gid & 255;
    Wt[(size_t)t * 65536 + (size_t)n * 256 + k] = f2b(Wsrc[(size_t)t * 65536 + gid]);
}

// ---------------------------------------------------------------------------
// Partition level 1a: coarse histogram (LDS-aggregated).
// ---------------------------------------------------------------------------
__global__ __launch_bounds__(256) void p1_hist(const int* __restrict__ adj,
                                               int* __restrict__ bucket_cnt) {
    __shared__ int lh[NB];
    const int t = blockIdx.y;
    const int tid = threadIdx.x;
    if (tid < NB) lh[tid] = 0;
    __syncthreads();

    const int* dstp = adj + (size_t)t * 2 * N_EDGES + N_EDGES;
    const int e0 = blockIdx.x * P1_CHUNK + tid * P1_EPT;
#pragma unroll
    for (int i = 0; i < P1_EPT; ++i) {
        const int e = e0 + i;
        if (e < N_EDGES) atomicAdd(&lh[dstp[e] >> BSH], 1);
    }
    __syncthreads();
    if (tid < NB && lh[tid] > 0) atomicAdd(&bucket_cnt[t * NB + tid], lh[tid]);
}

// ---------------------------------------------------------------------------
// Partition level 1b: scan 128 bucket counts per type. One block, 128 thr.
// ---------------------------------------------------------------------------
__global__ __launch_bounds__(128) void p1_scan(const int* __restrict__ bucket_cnt,
                                               int* __restrict__ bucket_ptr,
                                               int* __restrict__ bucket_cur) {
    __shared__ int s[NB];
    const int tid = threadIdx.x;
    for (int t = 0; t < NUM_T; ++t) {
        const int v = bucket_cnt[t * NB + tid];
        s[tid] = v;
        __syncthreads();
        for (int off = 1; off < NB; off <<= 1) {
            int o = (tid >= off) ? s[tid - off] : 0;
            __syncthreads();
            s[tid] += o;
            __syncthreads();
        }
        const int incl = s[tid];
        const int excl = incl - v;
        bucket_ptr[t * (NB + 1) + tid] = excl;
        bucket_cur[t * NB + tid] = excl;
        if (tid == NB - 1) bucket_ptr[t * (NB + 1) + NB] = incl;
        __syncthreads();
    }
}

// ---------------------------------------------------------------------------
// Partition level 1c v2: LDS counting-sort, then contiguous flush.
// ---------------------------------------------------------------------------
__global__ __launch_bounds__(256) void p1_scatter(const int* __restrict__ adj,
                                                  int* __restrict__ bucket_cur,
                                                  uint2* __restrict__ part) {
    __shared__ int lh[NB];
    __shared__ int loff[NB];
    __shared__ int lbase[NB];
    __shared__ uint2 buf[P1_CHUNK];   // 32 KB
    const int t = blockIdx.y;
    const int tid = threadIdx.x;
    const int lane = tid & 63;
    const int wave = tid >> 6;
    if (tid < NB) lh[tid] = 0;
    __syncthreads();

    const int* srcp = adj + (size_t)t * 2 * N_EDGES;
    const int* dstp = srcp + N_EDGES;
    const int e0 = blockIdx.x * P1_CHUNK + tid * P1_EPT;

    int es[P1_EPT], ed[P1_EPT], rk[P1_EPT];
#pragma unroll
    for (int i = 0; i < P1_EPT; ++i) {
        const int e = e0 + i;
        if (e < N_EDGES) {
            es[i] = srcp[e];
            ed[i] = dstp[e];
            rk[i] = atomicAdd(&lh[ed[i] >> BSH], 1);
        } else {
            ed[i] = -1;
        }
    }
    __syncthreads();

    // global window reserve (one atomic per non-empty bucket)
    if (tid < NB && lh[tid] > 0)
        lbase[tid] = atomicAdd(&bucket_cur[t * NB + tid], lh[tid]);
    // local exclusive scan of lh -> loff (wave 0, 2 buckets/lane)
    if (wave == 0) {
        const int c0 = lh[lane * 2], c1 = lh[lane * 2 + 1];
        const int s = c0 + c1;
        int run = s;
        for (int off = 1; off < 64; off <<= 1) {
            const int o = __shfl_up(run, off);
            if (lane >= off) run += o;
        }
        const int base = run - s;
        loff[lane * 2] = base;
        loff[lane * 2 + 1] = base + c0;
    }
    __syncthreads();

#pragma unroll
    for (int i = 0; i < P1_EPT; ++i)
        if (ed[i] >= 0)
            buf[loff[ed[i] >> BSH] + rk[i]] =
                make_uint2((unsigned)es[i], (unsigned)ed[i]);
    __syncthreads();

    uint2* pt = part + (size_t)t * N_EDGES;
    int nvalid = N_EDGES - blockIdx.x * P1_CHUNK;
    if (nvalid > P1_CHUNK) nvalid = P1_CHUNK;
    for (int idx = tid; idx < nvalid; idx += 256) {
        const uint2 e = buf[idx];
        const int b = (int)(e.y >> BSH);
        pt[lbase[b] + (idx - loff[b])] = e;
    }
}

// ---------------------------------------------------------------------------
// Partition level 2: per-bucket local CSR. One block per (bucket, type).
// ---------------------------------------------------------------------------
__global__ __launch_bounds__(256) void p2_csr(const uint2* __restrict__ part,
                                              const int* __restrict__ bucket_ptr,
                                              int* __restrict__ row_ptr_all,
                                              int* __restrict__ csr_all) {
    __shared__ int sc[BNODES];
    const int b = blockIdx.x;
    const int t = blockIdx.y;
    const int tid = threadIdx.x;
    const int lane = tid & 63;
    const int wave = tid >> 6;

    const uint2* pt = part + (size_t)t * N_EDGES;
    int* row_ptr = row_ptr_all + (size_t)t * (N_NODES + 1);
    int* csr = csr_all + (size_t)t * N_EDGES;

    const int bp0 = bucket_ptr[t * (NB + 1) + b];
    const int bp1 = bucket_ptr[t * (NB + 1) + b + 1];
    const int node0 = b * BNODES;
    int nn = N_NODES - node0; if (nn > BNODES) nn = BNODES;

    sc[tid] = 0; sc[tid + 256] = 0;
    __syncthreads();

    for (int idx = bp0 + tid; idx < bp1; idx += 256)
        atomicAdd(&sc[pt[idx].y - node0], 1);
    __syncthreads();

    if (wave == 0) {
        int v[8], ex[8];
        int s = 0;
#pragma unroll
        for (int i = 0; i < 8; ++i) { v[i] = sc[lane * 8 + i]; ex[i] = s; s += v[i]; }
        int run = s;
        for (int off = 1; off < 64; off <<= 1) {
            int o = __shfl_up(run, off);
            if (lane >= off) run += o;
        }
        const int base = run - s;
#pragma unroll
        for (int i = 0; i < 8; ++i) sc[lane * 8 + i] = base + ex[i];
    }
    __syncthreads();

    for (int i = tid; i < nn; i += 256) row_ptr[node0 + i] = bp0 + sc[i];
    if (b == NB_USED - 1 && tid == 0) row_ptr[N_NODES] = N_EDGES;
    __syncthreads();

    for (int idx = bp0 + tid; idx < bp1; idx += 256) {
        const uint2 e = pt[idx];
        const int pos = bp0 + atomicAdd(&sc[e.y - node0], 1);
        csr[pos] = (int)e.x;
    }
}

// ---------------------------------------------------------------------------
// GEMM (m97-style): 128x128 tile, BK=32, 4 waves, global_load_lds staging.
// ---------------------------------------------------------------------------
__global__ __launch_bounds__(256) void gemm_fused(const unsigned short* __restrict__ xb,
                                                  const unsigned short* __restrict__ Wt,
                                                  unsigned short* __restrict__ H) {
    __shared__ __attribute__((aligned(16))) unsigned short As[128 * 32];
    __shared__ __attribute__((aligned(16))) unsigned short Bs[128 * 32];

    const int tid  = threadIdx.x;
    const int wave = tid >> 6;
    const int lane = tid & 63;
    const int quad = lane >> 4;
    const int l16  = lane & 15;

    const int m0 = blockIdx.x * 128;
    const int n0 = blockIdx.y * 128;
    const int t  = blockIdx.z;

    const unsigned short* Bt = Wt + (size_t)t * 65536 + (size_t)n0 * W_IN;
    unsigned short* Hc = H + (size_t)t * N_NODES * W_OUT;

    const int moff = (wave >> 1) * 64;   // wave's row quadrant
    const int noff = (wave & 1) * 64;    // wave's col quadrant

    f32x4 acc[4][4] = {};

    const int srow = tid >> 2;
    const int sch  = (tid & 3) * 8;      // bf16 col offset
    int ar0 = m0 + srow;       if (ar0 > N_NODES - 1) ar0 = N_NODES - 1;
    int ar1 = m0 + 64 + srow;  if (ar1 > N_NODES - 1) ar1 = N_NODES - 1;
    const unsigned short* a0p = xb + (size_t)ar0 * W_IN + sch;
    const unsigned short* a1p = xb + (size_t)ar1 * W_IN + sch;
    const unsigned short* b0p = Bt + (size_t)srow * W_IN + sch;
    const unsigned short* b1p = Bt + (size_t)(64 + srow) * W_IN + sch;
#if defined(HAS_GLL)
    const int ldso0 = wave * 64 * 8;          // elems: wave-uniform base, i=0
    const int ldso1 = (256 + wave * 64) * 8;  // i=1
#endif

    for (int k0 = 0; k0 < W_IN; k0 += 32) {
#if defined(HAS_GLL)
        __builtin_amdgcn_global_load_lds(
            (const __attribute__((address_space(1))) void*)(a0p + k0),
            (__attribute__((address_space(3))) void*)(As + ldso0), 16, 0, 0);
        __builtin_amdgcn_global_load_lds(
            (const __attribute__((address_space(1))) void*)(a1p + k0),
            (__attribute__((address_space(3))) void*)(As + ldso1), 16, 0, 0);
        __builtin_amdgcn_global_load_lds(
            (const __attribute__((address_space(1))) void*)(b0p + k0),
            (__attribute__((address_space(3))) void*)(Bs + ldso0), 16, 0, 0);
        __builtin_amdgcn_global_load_lds(
            (const __attribute__((address_space(1))) void*)(b1p + k0),
            (__attribute__((address_space(3))) void*)(Bs + ldso1), 16, 0, 0);
#else
        {
            const uint4 av0 = *(const uint4*)(a0p + k0);
            const uint4 av1 = *(const uint4*)(a1p + k0);
            const uint4 bv0 = *(const uint4*)(b0p + k0);
            const uint4 bv1 = *(const uint4*)(b1p + k0);
            *(uint4*)&As[(size_t)tid * 8] = av0;
            *(uint4*)&As[2048 + (size_t)tid * 8] = av1;
            *(uint4*)&Bs[(size_t)tid * 8] = bv0;
            *(uint4*)&Bs[2048 + (size_t)tid * 8] = bv1;
        }
#endif
        __syncthreads();

        bf16x8 af[4], bfr[4];
#pragma unroll
        for (int mi = 0; mi < 4; ++mi)
            af[mi] = *(const bf16x8*)&As[(moff + mi * 16 + l16) * 32 + quad * 8];
#pragma unroll
        for (int ni = 0; ni < 4; ++ni)
            bfr[ni] = *(const bf16x8*)&Bs[(noff + ni * 16 + l16) * 32 + quad * 8];
#pragma unroll
        for (int mi = 0; mi < 4; ++mi)
#pragma unroll
            for (int ni = 0; ni < 4; ++ni)
                acc[mi][ni] = __builtin_amdgcn_mfma_f32_16x16x32_bf16(
                    af[mi], bfr[ni], acc[mi][ni], 0, 0, 0);
        __syncthreads();
    }

#pragma unroll
    for (int mi = 0; mi < 4; ++mi)
#pragma unroll
        for (int reg = 0; reg < 4; ++reg) {
            const int gr = m0 + moff + mi * 16 + quad * 4 + reg;
            if (gr < N_NODES)
#pragma unroll
                for (int ni = 0; ni < 4; ++ni)
                    Hc[(size_t)gr * W_OUT + n0 + noff + ni * 16 + l16] =
                        f2b(acc[mi][ni][reg]);
        }
}

// ---------------------------------------------------------------------------
// el/er as a memory-bound row-scan of H (L3-resident): one wave per node.
// ---------------------------------------------------------------------------
__global__ __launch_bounds__(256) void compute_elr(
    const unsigned short* __restrict__ H, const float* __restrict__ a_l,
    const float* __restrict__ a_r, float* __restrict__ el,
    float* __restrict__ er) {
    const int node = (blockIdx.x * blockDim.x + threadIdx.x) >> 6;
    if (node >= N_NODES) return;
    const int t = blockIdx.y;
    const int lane = threadIdx.x & 63;
    const int h = lane >> 3;       // head 0..7
    const int j8 = lane & 7;       // 8 lanes per head, 4 cols each

    const size_t row = (size_t)t * N_NODES + node;
    const uint2 u = *(const uint2*)(H + row * W_OUT + h * 32 + j8 * 4);
    const float4 av = *(const float4*)(a_l + t * 256 + h * 32 + j8 * 4);
    const float4 rv = *(const float4*)(a_r + t * 256 + h * 32 + j8 * 4);
    const float c0 = blo(u.x), c1 = bhi(u.x), c2 = blo(u.y), c3 = bhi(u.y);
    float pl = c0 * av.x + c1 * av.y + c2 * av.z + c3 * av.w;
    float pr = c0 * rv.x + c1 * rv.y + c2 * rv.z + c3 * rv.w;
#pragma unroll
    for (int off = 1; off < 8; off <<= 1) {
        pl += __shfl_xor(pl, off);
        pr += __shfl_xor(pr, off);
    }
    if (j8 == 0) el[row * HEADS + h] = pl;
    if (j8 == 1) er[row * HEADS + h] = pr;
}

// ---------------------------------------------------------------------------
// Gather, XCD-column-sharded: wave = (node, colhalf); colhalf is tied to the
// XCD group via blockIdx (r = bid&7 round-robins XCDs; r>>2 = colhalf), so
// each per-XCD L2 only streams a 12.8 MB column slice of H per type (halves
// the ~614 MB H L2-miss traffic of the full-row gather). Heads are column-
// aligned (head h = cols [32h,32h+32)), so GAT softmax per head needs no
// cross-colhalf communication. Semantic combine moves back to its own kernel.
// 4 edges in flight per wave (16 lanes x 8 cols each), 1-deep pipeline.
// ---------------------------------------------------------------------------
__global__ __launch_bounds__(256) void gat_gather_split(
    const int* __restrict__ csr_src, const int* __restrict__ row_ptr,
    const float* __restrict__ el, const float* __restrict__ er,
    const unsigned short* __restrict__ H, unsigned short* __restrict__ ot) {
    const int bid = blockIdx.x;
    const int q   = bid >> 3;          // 0..3124
    const int r   = bid & 7;           // XCD (empirical round-robin)
    const int ch  = r >> 2;            // colhalf 0/1 <-> XCD group
    const int sub = r & 3;
    const int node = (q * 4 + sub) * 4 + (threadIdx.x >> 6);
    if (node >= N_NODES) return;
    const int lane = threadIdx.x & 63;
    const int g    = lane >> 4;        // edge slot 0..3
    const int d16  = lane & 15;        // 8-col chunk within the 128-col half
    const int hh   = ch * 4 + (d16 >> 2);        // head
    const int cbase = ch * 128 + d16 * 8;        // column offset in H row

    float2 acc[NUM_T][4] = {};
    float ssum[NUM_T] = {};

#pragma unroll
    for (int t = 0; t < NUM_T; ++t) {
        const int* cs = csr_src + (size_t)t * N_EDGES;
        const int* rp = row_ptr + (size_t)t * (N_NODES + 1);
        const float* elc = el + (size_t)t * N_NODES * HEADS;
        const float* erc = er + (size_t)t * N_NODES * HEADS;
        const unsigned short* Hc = H + (size_t)t * N_NODES * W_OUT;

        const int beg = rp[node];
        const int deg = rp[node + 1] - beg;
        if (deg <= 0) continue;
        const float erv = erc[(size_t)node * HEADS + hh];

        int mysrc = (lane < deg) ? cs[beg + lane] : 0;
        const int nq = (deg + 3) >> 2;

        // prologue: quad 0 (edge e = g)
        int s0 = __shfl(mysrc, g);
        uint4 u0 = *(const uint4*)(Hc + (size_t)s0 * W_OUT + cbase);
        float e0 = elc[(size_t)s0 * HEADS + hh];

        for (int qd = 0; qd < nq; ++qd) {
            int s1 = 0; uint4 u1 = u0; float e1 = 0.f;
            const int q1 = qd + 1;
            if (q1 < nq) {
                if ((q1 & 15) == 0) {
                    const int base = beg + (q1 >> 4) * 64;
                    mysrc = (base + lane < beg + deg) ? cs[base + lane] : 0;
                }
                s1 = __shfl(mysrc, (4 * q1 + g) & 63);
                u1 = *(const uint4*)(Hc + (size_t)s1 * W_OUT + cbase);
                e1 = elc[(size_t)s1 * HEADS + hh];
            }
            float v = e0 + erv;
            v = (v > 0.f) ? v : NEG_SLOPE * v;
            const float w = (4 * qd + g < deg) ? __expf(v) : 0.f;
            acc[t][0].x += w * blo(u0.x); acc[t][0].y += w * bhi(u0.x);
            acc[t][1].x += w * blo(u0.y); acc[t][1].y += w * bhi(u0.y);
            acc[t][2].x += w * blo(u0.z); acc[t][2].y += w * bhi(u0.z);
            acc[t][3].x += w * blo(u0.w); acc[t][3].y += w * bhi(u0.w);
            ssum[t] += w;
            s0 = s1; u0 = u1; e0 = e1;
        }
    }

    // reduce across the 4 edge slots (xor 16, then 32)
#pragma unroll
    for (int t = 0; t < NUM_T; ++t) {
#pragma unroll
        for (int i = 0; i < 4; ++i) {
            acc[t][i].x += __shfl_xor(acc[t][i].x, 16);
            acc[t][i].x += __shfl_xor(acc[t][i].x, 32);
            acc[t][i].y += __shfl_xor(acc[t][i].y, 16);
            acc[t][i].y += __shfl_xor(acc[t][i].y, 32);
        }
        ssum[t] += __shfl_xor(ssum[t], 16);
        ssum[t] += __shfl_xor(ssum[t], 32);
    }

    if (g == 0) {   // lanes 0..15 hold the reduced values
#pragma unroll
        for (int t = 0; t < NUM_T; ++t) {
            const float inv = 1.f / (ssum[t] + 1e-9f);
            unsigned short o8[8];
            o8[0] = f2b(acc[t][0].x * inv); o8[1] = f2b(acc[t][0].y * inv);
            o8[2] = f2b(acc[t][1].x * inv); o8[3] = f2b(acc[t][1].y * inv);
            o8[4] = f2b(acc[t][2].x * inv); o8[5] = f2b(acc[t][2].y * inv);
            o8[6] = f2b(acc[t][3].x * inv); o8[7] = f2b(acc[t][3].y * inv);
            *(uint4*)(ot + ((size_t)t * N_NODES + node) * W_OUT + cbase) =
                *(const uint4*)o8;
        }
    }
}

// ---------------------------------------------------------------------------
// Semantic attention combine: bf16 ot [3][N][256] (contiguous), fp32 out.
// ---------------------------------------------------------------------------
__global__ __launch_bounds__(256) void combine(const unsigned short* __restrict__ ot,
                                               const float* __restrict__ bias,
                                               const float* __restrict__ att_w,
                                               const float* __restrict__ att_b,
                                               float* __restrict__ out) {
    const int gw = (blockIdx.x * blockDim.x + threadIdx.x) >> 6;
    const int lane = threadIdx.x & 63;
    if (gw >= N_NODES) return;

    const float4 aw = *(const float4*)(att_w + lane * 4);
    const size_t base = (size_t)gw * W_OUT + lane * 4;
    const size_t tstride = (size_t)N_NODES * W_OUT;

    float4 v[NUM_T];
    float p[NUM_T];
#pragma unroll
    for (int t = 0; t < NUM_T; ++t) {
        const uint2 u = *(const uint2*)(ot + t * tstride + base);
        const float4 bv = *(const float4*)(bias + t * W_OUT + lane * 4);
        float4 hv;
        hv.x = blo(u.x) + bv.x;
        hv.y = bhi(u.x) + bv.y;
        hv.z = blo(u.y) + bv.z;
        hv.w = bhi(u.y) + bv.w;
        v[t] = hv;
        p[t] = hv.x * aw.x + hv.y * aw.y + hv.z * aw.z + hv.w * aw.w;
    }
#pragma unroll
    for (int off = 1; off < 64; off <<= 1) {
        p[0] += __shfl_xor(p[0], off);
        p[1] += __shfl_xor(p[1], off);
        p[2] += __shfl_xor(p[2], off);
    }
    const float ab = att_b[0];
    const float a0 = p[0] + ab, a1 = p[1] + ab, a2 = p[2] + ab;
    float4 o;
    o.x = a0 * v[0].x + a1 * v[1].x + a2 * v[2].x;
    o.y = a0 * v[0].y + a1 * v[1].y + a2 * v[2].y;
    o.z = a0 * v[0].z + a1 * v[1].z + a2 * v[2].z;
    o.w = a0 * v[0].w + a1 * v[1].w + a2 * v[2].w;
    *(float4*)(out + base) = o;
}

// ---------------------------------------------------------------------------
extern "C" void kernel_launch(void* const* d_in, const int* in_sizes, int n_in,
                              void* d_out, int out_size, void* d_ws, size_t ws_size,
                              hipStream_t stream) {
    const float* x     = (const float*)d_in[0];
    const int*   adj   = (const int*)d_in[1];   // [3][2][N_EDGES]
    const float* Ws    = (const float*)d_in[2]; // [3][256][256]
    const float* a_l   = (const float*)d_in[3]; // [3][8][32]
    const float* a_r   = (const float*)d_in[4];
    const float* bias  = (const float*)d_in[5]; // [3][256]
    const float* att_w = (const float*)d_in[6]; // [256]
    const float* att_b = (const float*)d_in[7]; // [1]
    float* out = (float*)d_out;

    // Workspace (~200 MB; round 3 proved this fits). part (19.2 MB) aliases
    // ot[0]: part is consumed by p2_csr BEFORE gat_gather_split writes ot
    // (single stream, serial dispatches).
    char* w = (char*)d_ws;
    unsigned short* xb = (unsigned short*)w; w += (size_t)N_NODES * W_IN * 2;          // 25.6 MB
    unsigned short* H  = (unsigned short*)w; w += (size_t)NUM_T * N_NODES * W_OUT * 2; // 76.8 MB
    unsigned short* Wt = (unsigned short*)w; w += (size_t)NUM_T * 65536 * 2;           // 0.39 MB
    unsigned short* ot = (unsigned short*)w; w += (size_t)NUM_T * N_NODES * W_OUT * 2; // 76.8 MB
    float* el = (float*)w; w += (size_t)NUM_T * N_NODES * HEADS * 4;   // 4.8 MB
    float* er = (float*)w; w += (size_t)NUM_T * N_NODES * HEADS * 4;   // 4.8 MB
    int* csr_src = (int*)w; w += (size_t)NUM_T * N_EDGES * 4;          // 9.6 MB
    int* row_ptr = (int*)w; w += (size_t)NUM_T * (N_NODES + 1) * 4;
    int* bucket_cnt = (int*)w; w += NUM_T * NB * 4;
    int* bucket_ptr = (int*)w; w += NUM_T * (NB + 1) * 4;
    int* bucket_cur = (int*)w; w += NUM_T * NB * 4;
    uint2* part = (uint2*)ot;   // 19.2 MB alias into ot[0]

    // --- setup: converts + two-level CSR build (all types at once) ---
    hipMemsetAsync(bucket_cnt, 0, NUM_T * NB * sizeof(int), stream);
    convert_x<<<12500, 256, 0, stream>>>(x, xb);
    convert_W<<<dim3(256, NUM_T), 256, 0, stream>>>(Ws, Wt);
    p1_hist<<<dim3(P1_BLOCKS, NUM_T), 256, 0, stream>>>(adj, bucket_cnt);
    p1_scan<<<1, 128, 0, stream>>>(bucket_cnt, bucket_ptr, bucket_cur);
    p1_scatter<<<dim3(P1_BLOCKS, NUM_T), 256, 0, stream>>>(adj, bucket_cur, part);
    p2_csr<<<dim3(NB_USED, NUM_T), 256, 0, stream>>>(part, bucket_ptr, row_ptr,
                                                     csr_src);

    // --- all 3 gemms in one dispatch, 128x128 tiles ---
    gemm_fused<<<dim3(MT_BLOCKS, 2, NUM_T), 256, 0, stream>>>(xb, Wt, H);

    // --- el/er from H (memory-bound, L3-resident) ---
    compute_elr<<<dim3(GATHER_BLOCKS, NUM_T), 256, 0, stream>>>(H, a_l, a_r,
                                                                el, er);

    // --- gather, column-sharded across XCD groups -> ot (bf16) ---
    gat_gather_split<<<SPLIT_BLOCKS, 256, 0, stream>>>(
        csr_src, row_ptr, el, er, H, ot);

    // --- semantic attention combine -> fp32 out ---
    combine<<<GATHER_BLOCKS, 256, 0, stream>>>(ot, bias, att_w, att_b, out);
}

// Round 10
// 483.192 us; speedup vs baseline: 1.0427x; 1.0427x over previous
//
#include <hip/hip_runtime.h>

#define N_NODES 50000
#define W_IN    256
#define W_OUT   256
#define HEADS   8
#define NUM_T   3
#define N_EDGES 800000
#define NEG_SLOPE 0.2f

#define NB      128           // coarse buckets (98 used)
#define BSH     9             // bucket = dst >> 9  (512 nodes/bucket)
#define BNODES  512
#define P1_EPT  16            // edges per thread in partition kernels
#define P1_CHUNK (256 * P1_EPT)   // 4096 edges per block
#define P1_BLOCKS ((N_EDGES + P1_CHUNK - 1) / P1_CHUNK)  // 196
#define NB_USED ((N_NODES + BNODES - 1) / BNODES)        // 98

#define MT_BLOCKS ((N_NODES + 127) / 128)   // 391 M-tiles
#define GATHER_BLOCKS ((N_NODES + 3) / 4)   // 12500
#define GQ_NODES 12500                      // nodes per gather quarter
#define GQ_BLOCKS (GQ_NODES / 4)            // 3125 blocks per quarter

#if defined(__has_builtin)
#if __has_builtin(__builtin_amdgcn_global_load_lds)
#define HAS_GLL 1
#endif
#endif

typedef __attribute__((ext_vector_type(8))) short bf16x8;
typedef __attribute__((ext_vector_type(4))) float f32x4;

__device__ __forceinline__ unsigned short f2b(float f) {
    unsigned u = __float_as_uint(f);
    u = (u + 0x7fffu + ((u >> 16) & 1u)) >> 16;
    return (unsigned short)u;
}
__device__ __forceinline__ float blo(unsigned u) { return __uint_as_float(u << 16); }
__device__ __forceinline__ float bhi(unsigned u) { return __uint_as_float(u & 0xffff0000u); }

// ---------------------------------------------------------------------------
// x fp32 -> bf16 (RNE). 12500 blocks * 256 threads * 4 elems = 12.8M exact.
// ---------------------------------------------------------------------------
__global__ __launch_bounds__(256) void convert_x(const float* __restrict__ x,
                                                 unsigned short* __restrict__ xb) {
    const size_t i = ((size_t)blockIdx.x * 256 + threadIdx.x) * 4;
    const float4 v = *(const float4*)(x + i);
    ushort4 o;
    o.x = f2b(v.x); o.y = f2b(v.y); o.z = f2b(v.z); o.w = f2b(v.w);
    *(ushort4*)(xb + i) = o;
}

// ---------------------------------------------------------------------------
// W fp32 [t][k][n] -> bf16 transposed [t][n][k].
// ---------------------------------------------------------------------------
__global__ __launch_bounds__(256) void convert_W(const float* __restrict__ Wsrc,
                                                 unsigned short* __restrict__ Wt) {
    const int t = blockIdx.y;
    const int gid = blockIdx.x * 256 + threadIdx.x;  // 0..65535
    const int k = gid >> 8, n = gid & 255;
    Wt[(size_t)t * 65536 + (size_t)n * 256 + k] = f2b(Wsrc[(size_t)t * 65536 + gid]);
}

// ---------------------------------------------------------------------------
// Partition level 1a: coarse histogram (LDS-aggregated).
// ---------------------------------------------------------------------------
__global__ __launch_bounds__(256) void p1_hist(const int* __restrict__ adj,
                                               int* __restrict__ bucket_cnt) {
    __shared__ int lh[NB];
    const int t = blockIdx.y;
    const int tid = threadIdx.x;
    if (tid < NB) lh[tid] = 0;
    __syncthreads();

    const int* dstp = adj + (size_t)t * 2 * N_EDGES + N_EDGES;
    const int e0 = blockIdx.x * P1_CHUNK + tid * P1_EPT;
#pragma unroll
    for (int i = 0; i < P1_EPT; ++i) {
        const int e = e0 + i;
        if (e < N_EDGES) atomicAdd(&lh[dstp[e] >> BSH], 1);
    }
    __syncthreads();
    if (tid < NB && lh[tid] > 0) atomicAdd(&bucket_cnt[t * NB + tid], lh[tid]);
}

// ---------------------------------------------------------------------------
// Partition level 1b: scan 128 bucket counts per type. One block, 128 thr.
// ---------------------------------------------------------------------------
__global__ __launch_bounds__(128) void p1_scan(const int* __restrict__ bucket_cnt,
                                               int* __restrict__ bucket_ptr,
                                               int* __restrict__ bucket_cur) {
    __shared__ int s[NB];
    const int tid = threadIdx.x;
    for (int t = 0; t < NUM_T; ++t) {
        const int v = bucket_cnt[t * NB + tid];
        s[tid] = v;
        __syncthreads();
        for (int off = 1; off < NB; off <<= 1) {
            int o = (tid >= off) ? s[tid - off] : 0;
            __syncthreads();
            s[tid] += o;
            __syncthreads();
        }
        const int incl = s[tid];
        const int excl = incl - v;
        bucket_ptr[t * (NB + 1) + tid] = excl;
        bucket_cur[t * NB + tid] = excl;
        if (tid == NB - 1) bucket_ptr[t * (NB + 1) + NB] = incl;
        __syncthreads();
    }
}

// ---------------------------------------------------------------------------
// Partition level 1c v2: LDS counting-sort, then contiguous flush.
// ---------------------------------------------------------------------------
__global__ __launch_bounds__(256) void p1_scatter(const int* __restrict__ adj,
                                                  int* __restrict__ bucket_cur,
                                                  uint2* __restrict__ part) {
    __shared__ int lh[NB];
    __shared__ int loff[NB];
    __shared__ int lbase[NB];
    __shared__ uint2 buf[P1_CHUNK];   // 32 KB
    const int t = blockIdx.y;
    const int tid = threadIdx.x;
    const int lane = tid & 63;
    const int wave = tid >> 6;
    if (tid < NB) lh[tid] = 0;
    __syncthreads();

    const int* srcp = adj + (size_t)t * 2 * N_EDGES;
    const int* dstp = srcp + N_EDGES;
    const int e0 = blockIdx.x * P1_CHUNK + tid * P1_EPT;

    int es[P1_EPT], ed[P1_EPT], rk[P1_EPT];
#pragma unroll
    for (int i = 0; i < P1_EPT; ++i) {
        const int e = e0 + i;
        if (e < N_EDGES) {
            es[i] = srcp[e];
            ed[i] = dstp[e];
            rk[i] = atomicAdd(&lh[ed[i] >> BSH], 1);
        } else {
            ed[i] = -1;
        }
    }
    __syncthreads();

    // global window reserve (one atomic per non-empty bucket)
    if (tid < NB && lh[tid] > 0)
        lbase[tid] = atomicAdd(&bucket_cur[t * NB + tid], lh[tid]);
    // local exclusive scan of lh -> loff (wave 0, 2 buckets/lane)
    if (wave == 0) {
        const int c0 = lh[lane * 2], c1 = lh[lane * 2 + 1];
        const int s = c0 + c1;
        int run = s;
        for (int off = 1; off < 64; off <<= 1) {
            const int o = __shfl_up(run, off);
            if (lane >= off) run += o;
        }
        const int base = run - s;
        loff[lane * 2] = base;
        loff[lane * 2 + 1] = base + c0;
    }
    __syncthreads();

#pragma unroll
    for (int i = 0; i < P1_EPT; ++i)
        if (ed[i] >= 0)
            buf[loff[ed[i] >> BSH] + rk[i]] =
                make_uint2((unsigned)es[i], (unsigned)ed[i]);
    __syncthreads();

    uint2* pt = part + (size_t)t * N_EDGES;
    int nvalid = N_EDGES - blockIdx.x * P1_CHUNK;
    if (nvalid > P1_CHUNK) nvalid = P1_CHUNK;
    for (int idx = tid; idx < nvalid; idx += 256) {
        const uint2 e = buf[idx];
        const int b = (int)(e.y >> BSH);
        pt[lbase[b] + (idx - loff[b])] = e;
    }
}

// ---------------------------------------------------------------------------
// Partition level 2: per-bucket local CSR. One block per (bucket, type).
// ---------------------------------------------------------------------------
__global__ __launch_bounds__(256) void p2_csr(const uint2* __restrict__ part,
                                              const int* __restrict__ bucket_ptr,
                                              int* __restrict__ row_ptr_all,
                                              int* __restrict__ csr_all) {
    __shared__ int sc[BNODES];
    const int b = blockIdx.x;
    const int t = blockIdx.y;
    const int tid = threadIdx.x;
    const int lane = tid & 63;
    const int wave = tid >> 6;

    const uint2* pt = part + (size_t)t * N_EDGES;
    int* row_ptr = row_ptr_all + (size_t)t * (N_NODES + 1);
    int* csr = csr_all + (size_t)t * N_EDGES;

    const int bp0 = bucket_ptr[t * (NB + 1) + b];
    const int bp1 = bucket_ptr[t * (NB + 1) + b + 1];
    const int node0 = b * BNODES;
    int nn = N_NODES - node0; if (nn > BNODES) nn = BNODES;

    sc[tid] = 0; sc[tid + 256] = 0;
    __syncthreads();

    for (int idx = bp0 + tid; idx < bp1; idx += 256)
        atomicAdd(&sc[pt[idx].y - node0], 1);
    __syncthreads();

    if (wave == 0) {
        int v[8], ex[8];
        int s = 0;
#pragma unroll
        for (int i = 0; i < 8; ++i) { v[i] = sc[lane * 8 + i]; ex[i] = s; s += v[i]; }
        int run = s;
        for (int off = 1; off < 64; off <<= 1) {
            int o = __shfl_up(run, off);
            if (lane >= off) run += o;
        }
        const int base = run - s;
#pragma unroll
        for (int i = 0; i < 8; ++i) sc[lane * 8 + i] = base + ex[i];
    }
    __syncthreads();

    for (int i = tid; i < nn; i += 256) row_ptr[node0 + i] = bp0 + sc[i];
    if (b == NB_USED - 1 && tid == 0) row_ptr[N_NODES] = N_EDGES;
    __syncthreads();

    for (int idx = bp0 + tid; idx < bp1; idx += 256) {
        const uint2 e = pt[idx];
        const int pos = bp0 + atomicAdd(&sc[e.y - node0], 1);
        csr[pos] = (int)e.x;
    }
}

// ---------------------------------------------------------------------------
// GEMM (m97-style): 128x128 tile, BK=32, 4 waves, global_load_lds staging.
// ---------------------------------------------------------------------------
__global__ __launch_bounds__(256) void gemm_fused(const unsigned short* __restrict__ xb,
                                                  const unsigned short* __restrict__ Wt,
                                                  unsigned short* __restrict__ H) {
    __shared__ __attribute__((aligned(16))) unsigned short As[128 * 32];
    __shared__ __attribute__((aligned(16))) unsigned short Bs[128 * 32];

    const int tid  = threadIdx.x;
    const int wave = tid >> 6;
    const int lane = tid & 63;
    const int quad = lane >> 4;
    const int l16  = lane & 15;

    const int m0 = blockIdx.x * 128;
    const int n0 = blockIdx.y * 128;
    const int t  = blockIdx.z;

    const unsigned short* Bt = Wt + (size_t)t * 65536 + (size_t)n0 * W_IN;
    unsigned short* Hc = H + (size_t)t * N_NODES * W_OUT;

    const int moff = (wave >> 1) * 64;   // wave's row quadrant
    const int noff = (wave & 1) * 64;    // wave's col quadrant

    f32x4 acc[4][4] = {};

    const int srow = tid >> 2;
    const int sch  = (tid & 3) * 8;      // bf16 col offset
    int ar0 = m0 + srow;       if (ar0 > N_NODES - 1) ar0 = N_NODES - 1;
    int ar1 = m0 + 64 + srow;  if (ar1 > N_NODES - 1) ar1 = N_NODES - 1;
    const unsigned short* a0p = xb + (size_t)ar0 * W_IN + sch;
    const unsigned short* a1p = xb + (size_t)ar1 * W_IN + sch;
    const unsigned short* b0p = Bt + (size_t)srow * W_IN + sch;
    const unsigned short* b1p = Bt + (size_t)(64 + srow) * W_IN + sch;
#if defined(HAS_GLL)
    const int ldso0 = wave * 64 * 8;          // elems: wave-uniform base, i=0
    const int ldso1 = (256 + wave * 64) * 8;  // i=1
#endif

    for (int k0 = 0; k0 < W_IN; k0 += 32) {
#if defined(HAS_GLL)
        __builtin_amdgcn_global_load_lds(
            (const __attribute__((address_space(1))) void*)(a0p + k0),
            (__attribute__((address_space(3))) void*)(As + ldso0), 16, 0, 0);
        __builtin_amdgcn_global_load_lds(
            (const __attribute__((address_space(1))) void*)(a1p + k0),
            (__attribute__((address_space(3))) void*)(As + ldso1), 16, 0, 0);
        __builtin_amdgcn_global_load_lds(
            (const __attribute__((address_space(1))) void*)(b0p + k0),
            (__attribute__((address_space(3))) void*)(Bs + ldso0), 16, 0, 0);
        __builtin_amdgcn_global_load_lds(
            (const __attribute__((address_space(1))) void*)(b1p + k0),
            (__attribute__((address_space(3))) void*)(Bs + ldso1), 16, 0, 0);
#else
        {
            const uint4 av0 = *(const uint4*)(a0p + k0);
            const uint4 av1 = *(const uint4*)(a1p + k0);
            const uint4 bv0 = *(const uint4*)(b0p + k0);
            const uint4 bv1 = *(const uint4*)(b1p + k0);
            *(uint4*)&As[(size_t)tid * 8] = av0;
            *(uint4*)&As[2048 + (size_t)tid * 8] = av1;
            *(uint4*)&Bs[(size_t)tid * 8] = bv0;
            *(uint4*)&Bs[2048 + (size_t)tid * 8] = bv1;
        }
#endif
        __syncthreads();

        bf16x8 af[4], bfr[4];
#pragma unroll
        for (int mi = 0; mi < 4; ++mi)
            af[mi] = *(const bf16x8*)&As[(moff + mi * 16 + l16) * 32 + quad * 8];
#pragma unroll
        for (int ni = 0; ni < 4; ++ni)
            bfr[ni] = *(const bf16x8*)&Bs[(noff + ni * 16 + l16) * 32 + quad * 8];
#pragma unroll
        for (int mi = 0; mi < 4; ++mi)
#pragma unroll
            for (int ni = 0; ni < 4; ++ni)
                acc[mi][ni] = __builtin_amdgcn_mfma_f32_16x16x32_bf16(
                    af[mi], bfr[ni], acc[mi][ni], 0, 0, 0);
        __syncthreads();
    }

#pragma unroll
    for (int mi = 0; mi < 4; ++mi)
#pragma unroll
        for (int reg = 0; reg < 4; ++reg) {
            const int gr = m0 + moff + mi * 16 + quad * 4 + reg;
            if (gr < N_NODES)
#pragma unroll
                for (int ni = 0; ni < 4; ++ni)
                    Hc[(size_t)gr * W_OUT + n0 + noff + ni * 16 + l16] =
                        f2b(acc[mi][ni][reg]);
        }
}

// ---------------------------------------------------------------------------
// el/er as a memory-bound row-scan of H (L3-resident): one wave per node.
// ---------------------------------------------------------------------------
__global__ __launch_bounds__(256) void compute_elr(
    const unsigned short* __restrict__ H, const float* __restrict__ a_l,
    const float* __restrict__ a_r, float* __restrict__ el,
    float* __restrict__ er) {
    const int node = (blockIdx.x * blockDim.x + threadIdx.x) >> 6;
    if (node >= N_NODES) return;
    const int t = blockIdx.y;
    const int lane = threadIdx.x & 63;
    const int h = lane >> 3;       // head 0..7
    const int j8 = lane & 7;       // 8 lanes per head, 4 cols each

    const size_t row = (size_t)t * N_NODES + node;
    const uint2 u = *(const uint2*)(H + row * W_OUT + h * 32 + j8 * 4);
    const float4 av = *(const float4*)(a_l + t * 256 + h * 32 + j8 * 4);
    const float4 rv = *(const float4*)(a_r + t * 256 + h * 32 + j8 * 4);
    const float c0 = blo(u.x), c1 = bhi(u.x), c2 = blo(u.y), c3 = bhi(u.y);
    float pl = c0 * av.x + c1 * av.y + c2 * av.z + c3 * av.w;
    float pr = c0 * rv.x + c1 * rv.y + c2 * rv.z + c3 * rv.w;
#pragma unroll
    for (int off = 1; off < 8; off <<= 1) {
        pl += __shfl_xor(pl, off);
        pr += __shfl_xor(pr, off);
    }
    if (j8 == 0) el[row * HEADS + h] = pl;
    if (j8 == 1) er[row * HEADS + h] = pr;
}

// ---------------------------------------------------------------------------
// Gather v3 inner loop (proven 2-edge + 1-deep pipeline) accumulating into
// caller-owned registers. No epilogue here.
// ---------------------------------------------------------------------------
__device__ __forceinline__ void gather_accum(const int node, const int lane,
                                             const int* __restrict__ csr_src,
                                             const int* __restrict__ row_ptr,
                                             const float* __restrict__ el,
                                             const float* __restrict__ er,
                                             const unsigned short* __restrict__ H,
                                             float2 (&acc)[4], float& ssum) {
    const int half = lane >> 5;
    const int d8 = lane & 31;
    const int hh = d8 >> 2;

    const int beg = row_ptr[node];
    const int deg = row_ptr[node + 1] - beg;
    if (deg <= 0) return;
    const float erv = er[(size_t)node * HEADS + hh];

    int mysrc = (lane < deg) ? csr_src[beg + lane] : 0;
    const int npairs = (deg + 1) >> 1;

    // prologue: load pair 0 (edge ei = half)
    int src0 = __shfl(mysrc, half);
    uint4 u0 = *(const uint4*)(H + (size_t)src0 * W_OUT + d8 * 8);
    float elv0 = el[(size_t)src0 * HEADS + hh];

    for (int q = 0; q < npairs; ++q) {
        int src1 = 0; uint4 u1 = u0; float elv1 = 0.f;
        const int q1 = q + 1;
        if (q1 < npairs) {
            if ((q1 & 31) == 0) {
                const int cb = beg + (q1 >> 5) * 64;
                mysrc = (cb + lane < beg + deg) ? csr_src[cb + lane] : 0;
            }
            src1 = __shfl(mysrc, (2 * q1 + half) & 63);
            u1 = *(const uint4*)(H + (size_t)src1 * W_OUT + d8 * 8);
            elv1 = el[(size_t)src1 * HEADS + hh];
        }
        float v = elv0 + erv;
        v = (v > 0.f) ? v : NEG_SLOPE * v;
        const float w = (2 * q + half < deg) ? __expf(v) : 0.f;
        acc[0].x += w * blo(u0.x); acc[0].y += w * bhi(u0.x);
        acc[1].x += w * blo(u0.y); acc[1].y += w * bhi(u0.y);
        acc[2].x += w * blo(u0.z); acc[2].y += w * bhi(u0.z);
        acc[3].x += w * blo(u0.w); acc[3].y += w * bhi(u0.w);
        ssum += w;
        src0 = src1; u0 = u1; elv0 = elv1;
    }
}

// ---------------------------------------------------------------------------
// Gather for all 3 edge types + fused semantic-attention combine.
// node_base splits the node range into quarter dispatches (measurement:
// lowers the rocprof top-5 duration cutoff from ~205us to ~52us so the
// second-largest kernel becomes visible; work is identical).
// ---------------------------------------------------------------------------
__global__ __launch_bounds__(256) void gat_gather_all(
    const int node_base,
    const int* __restrict__ csr_src, const int* __restrict__ row_ptr,
    const float* __restrict__ el, const float* __restrict__ er,
    const unsigned short* __restrict__ H,
    const float* __restrict__ bias, const float* __restrict__ att_w,
    const float* __restrict__ att_b, float* __restrict__ out) {
    const int node = node_base + ((blockIdx.x * blockDim.x + threadIdx.x) >> 6);
    const int lane = threadIdx.x & 63;
    if (node >= N_NODES) return;

    float2 acc[NUM_T][4] = {};
    float ssum[NUM_T] = {};

#pragma unroll
    for (int t = 0; t < NUM_T; ++t)
        gather_accum(node, lane,
                     csr_src + (size_t)t * N_EDGES,
                     row_ptr + (size_t)t * (N_NODES + 1),
                     el + (size_t)t * N_NODES * HEADS,
                     er + (size_t)t * N_NODES * HEADS,
                     H + (size_t)t * N_NODES * W_OUT,
                     acc[t], ssum[t]);

    // cross-half reduce (lane ^ 32)
#pragma unroll
    for (int t = 0; t < NUM_T; ++t) {
#pragma unroll
        for (int i = 0; i < 4; ++i) {
            acc[t][i].x += __shfl_xor(acc[t][i].x, 32);
            acc[t][i].y += __shfl_xor(acc[t][i].y, 32);
        }
        ssum[t] += __shfl_xor(ssum[t], 32);
    }

    const int half = lane >> 5;
    const int d8 = lane & 31;
    if (half == 0) {
        const float4 aw0 = *(const float4*)(att_w + d8 * 8);
        const float4 aw1 = *(const float4*)(att_w + d8 * 8 + 4);
        float h[NUM_T][8];
        float p[NUM_T];
#pragma unroll
        for (int t = 0; t < NUM_T; ++t) {
            const float inv = 1.f / (ssum[t] + 1e-9f);
            const float4 b0 = *(const float4*)(bias + t * W_OUT + d8 * 8);
            const float4 b1 = *(const float4*)(bias + t * W_OUT + d8 * 8 + 4);
            h[t][0] = acc[t][0].x * inv + b0.x;
            h[t][1] = acc[t][0].y * inv + b0.y;
            h[t][2] = acc[t][1].x * inv + b0.z;
            h[t][3] = acc[t][1].y * inv + b0.w;
            h[t][4] = acc[t][2].x * inv + b1.x;
            h[t][5] = acc[t][2].y * inv + b1.y;
            h[t][6] = acc[t][3].x * inv + b1.z;
            h[t][7] = acc[t][3].y * inv + b1.w;
            p[t] = h[t][0] * aw0.x + h[t][1] * aw0.y + h[t][2] * aw0.z +
                   h[t][3] * aw0.w + h[t][4] * aw1.x + h[t][5] * aw1.y +
                   h[t][6] * aw1.z + h[t][7] * aw1.w;
        }
        // reduce semantic scores over the 32 active lanes
#pragma unroll
        for (int off = 1; off < 32; off <<= 1) {
            p[0] += __shfl_xor(p[0], off);
            p[1] += __shfl_xor(p[1], off);
            p[2] += __shfl_xor(p[2], off);
        }
        const float ab = att_b[0];
        const float a0 = p[0] + ab, a1 = p[1] + ab, a2 = p[2] + ab;
        float4 o0, o1;
        o0.x = a0 * h[0][0] + a1 * h[1][0] + a2 * h[2][0];
        o0.y = a0 * h[0][1] + a1 * h[1][1] + a2 * h[2][1];
        o0.z = a0 * h[0][2] + a1 * h[1][2] + a2 * h[2][2];
        o0.w = a0 * h[0][3] + a1 * h[1][3] + a2 * h[2][3];
        o1.x = a0 * h[0][4] + a1 * h[1][4] + a2 * h[2][4];
        o1.y = a0 * h[0][5] + a1 * h[1][5] + a2 * h[2][5];
        o1.z = a0 * h[0][6] + a1 * h[1][6] + a2 * h[2][6];
        o1.w = a0 * h[0][7] + a1 * h[1][7] + a2 * h[2][7];
        *(float4*)(out + (size_t)node * W_OUT + d8 * 8) = o0;
        *(float4*)(out + (size_t)node * W_OUT + d8 * 8 + 4) = o1;
    }
}

// ---------------------------------------------------------------------------
extern "C" void kernel_launch(void* const* d_in, const int* in_sizes, int n_in,
                              void* d_out, int out_size, void* d_ws, size_t ws_size,
                              hipStream_t stream) {
    const float* x     = (const float*)d_in[0];
    const int*   adj   = (const int*)d_in[1];   // [3][2][N_EDGES]
    const float* Ws    = (const float*)d_in[2]; // [3][256][256]
    const float* a_l   = (const float*)d_in[3]; // [3][8][32]
    const float* a_r   = (const float*)d_in[4];
    const float* bias  = (const float*)d_in[5]; // [3][256]
    const float* att_w = (const float*)d_in[6]; // [256]
    const float* att_b = (const float*)d_in[7]; // [1]
    float* out = (float*)d_out;

    // Workspace (~123 MB). part (19.2 MB) aliases H[0]: part is consumed by
    // p2_csr BEFORE gemm_fused writes H (single stream, serial dispatches).
    char* w = (char*)d_ws;
    unsigned short* xb = (unsigned short*)w; w += (size_t)N_NODES * W_IN * 2;          // 25.6 MB
    unsigned short* H  = (unsigned short*)w; w += (size_t)NUM_T * N_NODES * W_OUT * 2; // 76.8 MB
    unsigned short* Wt = (unsigned short*)w; w += (size_t)NUM_T * 65536 * 2;           // 0.39 MB
    float* el = (float*)w; w += (size_t)NUM_T * N_NODES * HEADS * 4;   // 4.8 MB
    float* er = (float*)w; w += (size_t)NUM_T * N_NODES * HEADS * 4;   // 4.8 MB
    int* csr_src = (int*)w; w += (size_t)NUM_T * N_EDGES * 4;          // 9.6 MB
    int* row_ptr = (int*)w; w += (size_t)NUM_T * (N_NODES + 1) * 4;
    int* bucket_cnt = (int*)w; w += NUM_T * NB * 4;
    int* bucket_ptr = (int*)w; w += NUM_T * (NB + 1) * 4;
    int* bucket_cur = (int*)w; w += NUM_T * NB * 4;
    uint2* part = (uint2*)H;   // 19.2 MB alias into H[0]

    // --- setup: converts + two-level CSR build (all types at once) ---
    hipMemsetAsync(bucket_cnt, 0, NUM_T * NB * sizeof(int), stream);
    convert_x<<<12500, 256, 0, stream>>>(x, xb);
    convert_W<<<dim3(256, NUM_T), 256, 0, stream>>>(Ws, Wt);
    p1_hist<<<dim3(P1_BLOCKS, NUM_T), 256, 0, stream>>>(adj, bucket_cnt);
    p1_scan<<<1, 128, 0, stream>>>(bucket_cnt, bucket_ptr, bucket_cur);
    p1_scatter<<<dim3(P1_BLOCKS, NUM_T), 256, 0, stream>>>(adj, bucket_cur, part);
    p2_csr<<<dim3(NB_USED, NUM_T), 256, 0, stream>>>(part, bucket_ptr, row_ptr,
                                                     csr_src);

    // --- all 3 gemms in one dispatch, 128x128 tiles (overwrites part alias) ---
    gemm_fused<<<dim3(MT_BLOCKS, 2, NUM_T), 256, 0, stream>>>(xb, Wt, H);

    // --- el/er from H (memory-bound, L3-resident) ---
    compute_elr<<<dim3(GATHER_BLOCKS, NUM_T), 256, 0, stream>>>(H, a_l, a_r,
                                                                el, er);

    // --- gather all types + semantic combine fused, fp32 out ---
    // Split into 4 node-range quarters: identical work, lowers the rocprof
    // top-5 cutoff to ~52us so the second-largest kernel becomes measurable.
    for (int qrt = 0; qrt < 4; ++qrt)
        gat_gather_all<<<GQ_BLOCKS, 256, 0, stream>>>(
            qrt * GQ_NODES, csr_src, row_ptr, el, er, H, bias, att_w, att_b,
            out);
}

// Round 11
// 457.948 us; speedup vs baseline: 1.1001x; 1.0551x over previous
//
#include <hip/hip_runtime.h>

#define N_NODES 50000
#define W_IN    256
#define W_OUT   256
#define HEADS   8
#define NUM_T   3
#define N_EDGES 800000
#define NEG_SLOPE 0.2f

#define NB      128           // coarse buckets (98 used)
#define BSH     9             // bucket = dst >> 9  (512 nodes/bucket)
#define BNODES  512
#define P1_EPT  16            // edges per thread in partition kernels
#define P1_CHUNK (256 * P1_EPT)   // 4096 edges per block
#define P1_BLOCKS ((N_EDGES + P1_CHUNK - 1) / P1_CHUNK)  // 196
#define NB_USED ((N_NODES + BNODES - 1) / BNODES)        // 98

#define MT_BLOCKS ((N_NODES + 127) / 128)   // 391 M-tiles
#define GATHER_BLOCKS ((N_NODES + 3) / 4)   // 12500

// prep dispatch block ranges
#define PREP_CX   12500                      // convert_x blocks
#define PREP_CW   768                        // convert_W blocks (3*65536/256)
#define PREP_HIST (P1_BLOCKS * NUM_T)        // 588 histogram blocks
#define PREP_BLOCKS (PREP_CX + PREP_CW + PREP_HIST)   // 13856

#define SG_BLOCKS (1 + MT_BLOCKS * 2 * NUM_T)         // 1 scan + 2346 gemm
#define SE_SCAT   (P1_BLOCKS * NUM_T)                 // 588
#define SE_ELR    (GATHER_BLOCKS * NUM_T)             // 37500
#define SE_BLOCKS (SE_SCAT + SE_ELR)                  // 38088

#if defined(__has_builtin)
#if __has_builtin(__builtin_amdgcn_global_load_lds)
#define HAS_GLL 1
#endif
#endif

typedef __attribute__((ext_vector_type(8))) short bf16x8;
typedef __attribute__((ext_vector_type(4))) float f32x4;

__device__ __forceinline__ unsigned short f2b(float f) {
    unsigned u = __float_as_uint(f);
    u = (u + 0x7fffu + ((u >> 16) & 1u)) >> 16;
    return (unsigned short)u;
}
__device__ __forceinline__ float blo(unsigned u) { return __uint_as_float(u << 16); }
__device__ __forceinline__ float bhi(unsigned u) { return __uint_as_float(u & 0xffff0000u); }

// ---------------------------------------------------------------------------
// Dispatch 1: prep = convert_x || convert_W || per-block dst histogram.
// Histogram writes per-(type,chunk) counts to hist_mat (no init, no global
// atomics) -> removes the memset dispatch and bucket_cur entirely.
// ---------------------------------------------------------------------------
__global__ __launch_bounds__(256) void prep(const float* __restrict__ x,
                                            unsigned short* __restrict__ xb,
                                            const float* __restrict__ Wsrc,
                                            unsigned short* __restrict__ Wt,
                                            const int* __restrict__ adj,
                                            int* __restrict__ hist_mat) {
    __shared__ int lh[NB];
    const int b = blockIdx.x;
    const int tid = threadIdx.x;

    if (b < PREP_CX) {
        // ---- convert_x: 12500 blocks * 256 thr * 4 elems = 12.8M exact ----
        const size_t i = ((size_t)b * 256 + tid) * 4;
        const float4 v = *(const float4*)(x + i);
        ushort4 o;
        o.x = f2b(v.x); o.y = f2b(v.y); o.z = f2b(v.z); o.w = f2b(v.w);
        *(ushort4*)(xb + i) = o;
        return;
    }
    if (b < PREP_CX + PREP_CW) {
        // ---- convert_W fp32 [t][k][n] -> bf16 [t][n][k] ----
        const int idx = (b - PREP_CX) * 256 + tid;   // 0..196607
        const int t = idx >> 16;
        const int gid = idx & 65535;
        const int k = gid >> 8, n = gid & 255;
        Wt[(size_t)t * 65536 + (size_t)n * 256 + k] =
            f2b(Wsrc[(size_t)t * 65536 + gid]);
        return;
    }
    // ---- per-block histogram: hb = (t, chunk c) ----
    const int hb = b - PREP_CX - PREP_CW;            // 0..587
    const int t = hb / P1_BLOCKS;
    const int c = hb % P1_BLOCKS;
    if (tid < NB) lh[tid] = 0;
    __syncthreads();

    const int* dstp = adj + (size_t)t * 2 * N_EDGES + N_EDGES;
    const int e0 = c * P1_CHUNK + tid * P1_EPT;
#pragma unroll
    for (int i = 0; i < P1_EPT; ++i) {
        const int e = e0 + i;
        if (e < N_EDGES) atomicAdd(&lh[dstp[e] >> BSH], 1);
    }
    __syncthreads();
    if (tid < NB)
        hist_mat[((size_t)t * P1_BLOCKS + c) * NB + tid] = lh[tid];
}

// ---------------------------------------------------------------------------
// Dispatch 2: block 0 = scan (hist_mat -> in-place per-block exclusive
// offsets + bucket_ptr); blocks 1.. = 128x128 MFMA gemm (m97-style,
// global_load_lds staging). Scan work hides under the gemm.
// ---------------------------------------------------------------------------
__global__ __launch_bounds__(256) void scan_gemm(int* __restrict__ hist_mat,
                                                 int* __restrict__ bucket_ptr,
                                                 const unsigned short* __restrict__ xb,
                                                 const unsigned short* __restrict__ Wt,
                                                 unsigned short* __restrict__ H) {
    __shared__ __attribute__((aligned(16))) unsigned short As[128 * 32];
    __shared__ __attribute__((aligned(16))) unsigned short Bs[128 * 32];
    const int tid = threadIdx.x;

    if (blockIdx.x == 0) {
        // ---- scan phase ----
        int* s = (int*)As;
        for (int t = 0; t < NUM_T; ++t) {
            int tot = 0;
            if (tid < NB) {
                int run = 0;
                for (int c = 0; c < P1_BLOCKS; ++c) {
                    const size_t ix = ((size_t)t * P1_BLOCKS + c) * NB + tid;
                    const int v = hist_mat[ix];
                    hist_mat[ix] = run;    // per-block exclusive offset
                    run += v;
                }
                tot = run;
                s[tid] = tot;
            }
            __syncthreads();
            for (int off = 1; off < NB; off <<= 1) {
                int o = 0;
                if (tid < NB && tid >= off) o = s[tid - off];
                __syncthreads();
                if (tid < NB) s[tid] += o;
                __syncthreads();
            }
            if (tid < NB) {
                bucket_ptr[t * (NB + 1) + tid] = s[tid] - tot;   // exclusive
                if (tid == NB - 1) bucket_ptr[t * (NB + 1) + NB] = s[tid];
            }
            __syncthreads();
        }
        return;
    }

    // ---- gemm phase ----
    const int g = blockIdx.x - 1;                 // 0..2345
    const int mt = g % MT_BLOCKS;
    const int nh = (g / MT_BLOCKS) & 1;
    const int t  = g / (MT_BLOCKS * 2);

    const int wave = tid >> 6;
    const int lane = tid & 63;
    const int quad = lane >> 4;
    const int l16  = lane & 15;

    const int m0 = mt * 128;
    const int n0 = nh * 128;

    const unsigned short* Bt = Wt + (size_t)t * 65536 + (size_t)n0 * W_IN;
    unsigned short* Hc = H + (size_t)t * N_NODES * W_OUT;

    const int moff = (wave >> 1) * 64;
    const int noff = (wave & 1) * 64;

    f32x4 acc[4][4] = {};

    const int srow = tid >> 2;
    const int sch  = (tid & 3) * 8;
    int ar0 = m0 + srow;       if (ar0 > N_NODES - 1) ar0 = N_NODES - 1;
    int ar1 = m0 + 64 + srow;  if (ar1 > N_NODES - 1) ar1 = N_NODES - 1;
    const unsigned short* a0p = xb + (size_t)ar0 * W_IN + sch;
    const unsigned short* a1p = xb + (size_t)ar1 * W_IN + sch;
    const unsigned short* b0p = Bt + (size_t)srow * W_IN + sch;
    const unsigned short* b1p = Bt + (size_t)(64 + srow) * W_IN + sch;
#if defined(HAS_GLL)
    const int ldso0 = wave * 64 * 8;
    const int ldso1 = (256 + wave * 64) * 8;
#endif

    for (int k0 = 0; k0 < W_IN; k0 += 32) {
#if defined(HAS_GLL)
        __builtin_amdgcn_global_load_lds(
            (const __attribute__((address_space(1))) void*)(a0p + k0),
            (__attribute__((address_space(3))) void*)(As + ldso0), 16, 0, 0);
        __builtin_amdgcn_global_load_lds(
            (const __attribute__((address_space(1))) void*)(a1p + k0),
            (__attribute__((address_space(3))) void*)(As + ldso1), 16, 0, 0);
        __builtin_amdgcn_global_load_lds(
            (const __attribute__((address_space(1))) void*)(b0p + k0),
            (__attribute__((address_space(3))) void*)(Bs + ldso0), 16, 0, 0);
        __builtin_amdgcn_global_load_lds(
            (const __attribute__((address_space(1))) void*)(b1p + k0),
            (__attribute__((address_space(3))) void*)(Bs + ldso1), 16, 0, 0);
#else
        {
            const uint4 av0 = *(const uint4*)(a0p + k0);
            const uint4 av1 = *(const uint4*)(a1p + k0);
            const uint4 bv0 = *(const uint4*)(b0p + k0);
            const uint4 bv1 = *(const uint4*)(b1p + k0);
            *(uint4*)&As[(size_t)tid * 8] = av0;
            *(uint4*)&As[2048 + (size_t)tid * 8] = av1;
            *(uint4*)&Bs[(size_t)tid * 8] = bv0;
            *(uint4*)&Bs[2048 + (size_t)tid * 8] = bv1;
        }
#endif
        __syncthreads();

        bf16x8 af[4], bfr[4];
#pragma unroll
        for (int mi = 0; mi < 4; ++mi)
            af[mi] = *(const bf16x8*)&As[(moff + mi * 16 + l16) * 32 + quad * 8];
#pragma unroll
        for (int ni = 0; ni < 4; ++ni)
            bfr[ni] = *(const bf16x8*)&Bs[(noff + ni * 16 + l16) * 32 + quad * 8];
#pragma unroll
        for (int mi = 0; mi < 4; ++mi)
#pragma unroll
            for (int ni = 0; ni < 4; ++ni)
                acc[mi][ni] = __builtin_amdgcn_mfma_f32_16x16x32_bf16(
                    af[mi], bfr[ni], acc[mi][ni], 0, 0, 0);
        __syncthreads();
    }

#pragma unroll
    for (int mi = 0; mi < 4; ++mi)
#pragma unroll
        for (int reg = 0; reg < 4; ++reg) {
            const int gr = m0 + moff + mi * 16 + quad * 4 + reg;
            if (gr < N_NODES)
#pragma unroll
                for (int ni = 0; ni < 4; ++ni)
                    Hc[(size_t)gr * W_OUT + n0 + noff + ni * 16 + l16] =
                        f2b(acc[mi][ni][reg]);
        }
}

// ---------------------------------------------------------------------------
// Dispatch 3: scatter (atomic-free window placement via scanned hist_mat)
// || compute_elr (reads H from dispatch 2). Independent block ranges.
// ---------------------------------------------------------------------------
__global__ __launch_bounds__(256) void scatter_elr(
    const int* __restrict__ adj, const int* __restrict__ bucket_ptr,
    const int* __restrict__ hist_mat, uint2* __restrict__ part,
    const unsigned short* __restrict__ H, const float* __restrict__ a_l,
    const float* __restrict__ a_r, float* __restrict__ el,
    float* __restrict__ er) {
    __shared__ int lh[NB];
    __shared__ int loff[NB];
    __shared__ int lbase[NB];
    __shared__ uint2 buf[P1_CHUNK];   // 32 KB
    const int b = blockIdx.x;
    const int tid = threadIdx.x;

    if (b >= SE_SCAT) {
        // ---- elr phase: one wave per (type, node) ----
        const int eb = b - SE_SCAT;               // 0..37499
        const int t = eb / GATHER_BLOCKS;
        const int xbk = eb % GATHER_BLOCKS;
        const int node = xbk * 4 + (tid >> 6);
        if (node >= N_NODES) return;
        const int lane = tid & 63;
        const int h = lane >> 3;
        const int j8 = lane & 7;

        const size_t row = (size_t)t * N_NODES + node;
        const uint2 u = *(const uint2*)(H + row * W_OUT + h * 32 + j8 * 4);
        const float4 av = *(const float4*)(a_l + t * 256 + h * 32 + j8 * 4);
        const float4 rv = *(const float4*)(a_r + t * 256 + h * 32 + j8 * 4);
        const float c0 = blo(u.x), c1 = bhi(u.x), c2 = blo(u.y), c3 = bhi(u.y);
        float pl = c0 * av.x + c1 * av.y + c2 * av.z + c3 * av.w;
        float pr = c0 * rv.x + c1 * rv.y + c2 * rv.z + c3 * rv.w;
#pragma unroll
        for (int off = 1; off < 8; off <<= 1) {
            pl += __shfl_xor(pl, off);
            pr += __shfl_xor(pr, off);
        }
        if (j8 == 0) el[row * HEADS + h] = pl;
        if (j8 == 1) er[row * HEADS + h] = pr;
        return;
    }

    // ---- scatter phase: LDS counting-sort + contiguous flush ----
    const int t = b / P1_BLOCKS;
    const int c = b % P1_BLOCKS;
    const int lane = tid & 63;
    const int wave = tid >> 6;
    if (tid < NB) lh[tid] = 0;
    __syncthreads();

    const int* srcp = adj + (size_t)t * 2 * N_EDGES;
    const int* dstp = srcp + N_EDGES;
    const int e0 = c * P1_CHUNK + tid * P1_EPT;

    int es[P1_EPT], ed[P1_EPT], rk[P1_EPT];
#pragma unroll
    for (int i = 0; i < P1_EPT; ++i) {
        const int e = e0 + i;
        if (e < N_EDGES) {
            es[i] = srcp[e];
            ed[i] = dstp[e];
            rk[i] = atomicAdd(&lh[ed[i] >> BSH], 1);
        } else {
            ed[i] = -1;
        }
    }
    __syncthreads();

    // deterministic global window base: bucket_ptr + scanned per-block offset
    if (tid < NB)
        lbase[tid] = bucket_ptr[t * (NB + 1) + tid] +
                     hist_mat[((size_t)t * P1_BLOCKS + c) * NB + tid];
    // local exclusive scan of lh -> loff (wave 0, 2 buckets/lane)
    if (wave == 0) {
        const int c0 = lh[lane * 2], c1 = lh[lane * 2 + 1];
        const int s = c0 + c1;
        int run = s;
        for (int off = 1; off < 64; off <<= 1) {
            const int o = __shfl_up(run, off);
            if (lane >= off) run += o;
        }
        const int base = run - s;
        loff[lane * 2] = base;
        loff[lane * 2 + 1] = base + c0;
    }
    __syncthreads();

#pragma unroll
    for (int i = 0; i < P1_EPT; ++i)
        if (ed[i] >= 0)
            buf[loff[ed[i] >> BSH] + rk[i]] =
                make_uint2((unsigned)es[i], (unsigned)ed[i]);
    __syncthreads();

    uint2* pt = part + (size_t)t * N_EDGES;
    int nvalid = N_EDGES - c * P1_CHUNK;
    if (nvalid > P1_CHUNK) nvalid = P1_CHUNK;
    for (int idx = tid; idx < nvalid; idx += 256) {
        const uint2 e = buf[idx];
        const int bb = (int)(e.y >> BSH);
        pt[lbase[bb] + (idx - loff[bb])] = e;
    }
}

// ---------------------------------------------------------------------------
// Dispatch 4: per-bucket local CSR. One block per (bucket, type).
// ---------------------------------------------------------------------------
__global__ __launch_bounds__(256) void p2_csr(const uint2* __restrict__ part,
                                              const int* __restrict__ bucket_ptr,
                                              int* __restrict__ row_ptr_all,
                                              int* __restrict__ csr_all) {
    __shared__ int sc[BNODES];
    const int b = blockIdx.x;
    const int t = blockIdx.y;
    const int tid = threadIdx.x;
    const int lane = tid & 63;
    const int wave = tid >> 6;

    const uint2* pt = part + (size_t)t * N_EDGES;
    int* row_ptr = row_ptr_all + (size_t)t * (N_NODES + 1);
    int* csr = csr_all + (size_t)t * N_EDGES;

    const int bp0 = bucket_ptr[t * (NB + 1) + b];
    const int bp1 = bucket_ptr[t * (NB + 1) + b + 1];
    const int node0 = b * BNODES;
    int nn = N_NODES - node0; if (nn > BNODES) nn = BNODES;

    sc[tid] = 0; sc[tid + 256] = 0;
    __syncthreads();

    for (int idx = bp0 + tid; idx < bp1; idx += 256)
        atomicAdd(&sc[pt[idx].y - node0], 1);
    __syncthreads();

    if (wave == 0) {
        int v[8], ex[8];
        int s = 0;
#pragma unroll
        for (int i = 0; i < 8; ++i) { v[i] = sc[lane * 8 + i]; ex[i] = s; s += v[i]; }
        int run = s;
        for (int off = 1; off < 64; off <<= 1) {
            int o = __shfl_up(run, off);
            if (lane >= off) run += o;
        }
        const int base = run - s;
#pragma unroll
        for (int i = 0; i < 8; ++i) sc[lane * 8 + i] = base + ex[i];
    }
    __syncthreads();

    for (int i = tid; i < nn; i += 256) row_ptr[node0 + i] = bp0 + sc[i];
    if (b == NB_USED - 1 && tid == 0) row_ptr[N_NODES] = N_EDGES;
    __syncthreads();

    for (int idx = bp0 + tid; idx < bp1; idx += 256) {
        const uint2 e = pt[idx];
        const int pos = bp0 + atomicAdd(&sc[e.y - node0], 1);
        csr[pos] = (int)e.x;
    }
}

// ---------------------------------------------------------------------------
// Gather v3 inner loop (proven 2-edge + 1-deep pipeline).
// ---------------------------------------------------------------------------
__device__ __forceinline__ void gather_accum(const int node, const int lane,
                                             const int* __restrict__ csr_src,
                                             const int* __restrict__ row_ptr,
                                             const float* __restrict__ el,
                                             const float* __restrict__ er,
                                             const unsigned short* __restrict__ H,
                                             float2 (&acc)[4], float& ssum) {
    const int half = lane >> 5;
    const int d8 = lane & 31;
    const int hh = d8 >> 2;

    const int beg = row_ptr[node];
    const int deg = row_ptr[node + 1] - beg;
    if (deg <= 0) return;
    const float erv = er[(size_t)node * HEADS + hh];

    int mysrc = (lane < deg) ? csr_src[beg + lane] : 0;
    const int npairs = (deg + 1) >> 1;

    int src0 = __shfl(mysrc, half);
    uint4 u0 = *(const uint4*)(H + (size_t)src0 * W_OUT + d8 * 8);
    float elv0 = el[(size_t)src0 * HEADS + hh];

    for (int q = 0; q < npairs; ++q) {
        int src1 = 0; uint4 u1 = u0; float elv1 = 0.f;
        const int q1 = q + 1;
        if (q1 < npairs) {
            if ((q1 & 31) == 0) {
                const int cb = beg + (q1 >> 5) * 64;
                mysrc = (cb + lane < beg + deg) ? csr_src[cb + lane] : 0;
            }
            src1 = __shfl(mysrc, (2 * q1 + half) & 63);
            u1 = *(const uint4*)(H + (size_t)src1 * W_OUT + d8 * 8);
            elv1 = el[(size_t)src1 * HEADS + hh];
        }
        float v = elv0 + erv;
        v = (v > 0.f) ? v : NEG_SLOPE * v;
        const float w = (2 * q + half < deg) ? __expf(v) : 0.f;
        acc[0].x += w * blo(u0.x); acc[0].y += w * bhi(u0.x);
        acc[1].x += w * blo(u0.y); acc[1].y += w * bhi(u0.y);
        acc[2].x += w * blo(u0.z); acc[2].y += w * bhi(u0.z);
        acc[3].x += w * blo(u0.w); acc[3].y += w * bhi(u0.w);
        ssum += w;
        src0 = src1; u0 = u1; elv0 = elv1;
    }
}

// ---------------------------------------------------------------------------
// Dispatch 5: gather all 3 edge types + fused semantic-attention combine.
// ---------------------------------------------------------------------------
__global__ __launch_bounds__(256) void gat_gather_all(
    const int* __restrict__ csr_src, const int* __restrict__ row_ptr,
    const float* __restrict__ el, const float* __restrict__ er,
    const unsigned short* __restrict__ H,
    const float* __restrict__ bias, const float* __restrict__ att_w,
    const float* __restrict__ att_b, float* __restrict__ out) {
    const int node = (blockIdx.x * blockDim.x + threadIdx.x) >> 6;
    const int lane = threadIdx.x & 63;
    if (node >= N_NODES) return;

    float2 acc[NUM_T][4] = {};
    float ssum[NUM_T] = {};

#pragma unroll
    for (int t = 0; t < NUM_T; ++t)
        gather_accum(node, lane,
                     csr_src + (size_t)t * N_EDGES,
                     row_ptr + (size_t)t * (N_NODES + 1),
                     el + (size_t)t * N_NODES * HEADS,
                     er + (size_t)t * N_NODES * HEADS,
                     H + (size_t)t * N_NODES * W_OUT,
                     acc[t], ssum[t]);

#pragma unroll
    for (int t = 0; t < NUM_T; ++t) {
#pragma unroll
        for (int i = 0; i < 4; ++i) {
            acc[t][i].x += __shfl_xor(acc[t][i].x, 32);
            acc[t][i].y += __shfl_xor(acc[t][i].y, 32);
        }
        ssum[t] += __shfl_xor(ssum[t], 32);
    }

    const int half = lane >> 5;
    const int d8 = lane & 31;
    if (half == 0) {
        const float4 aw0 = *(const float4*)(att_w + d8 * 8);
        const float4 aw1 = *(const float4*)(att_w + d8 * 8 + 4);
        float h[NUM_T][8];
        float p[NUM_T];
#pragma unroll
        for (int t = 0; t < NUM_T; ++t) {
            const float inv = 1.f / (ssum[t] + 1e-9f);
            const float4 b0 = *(const float4*)(bias + t * W_OUT + d8 * 8);
            const float4 b1 = *(const float4*)(bias + t * W_OUT + d8 * 8 + 4);
            h[t][0] = acc[t][0].x * inv + b0.x;
            h[t][1] = acc[t][0].y * inv + b0.y;
            h[t][2] = acc[t][1].x * inv + b0.z;
            h[t][3] = acc[t][1].y * inv + b0.w;
            h[t][4] = acc[t][2].x * inv + b1.x;
            h[t][5] = acc[t][2].y * inv + b1.y;
            h[t][6] = acc[t][3].x * inv + b1.z;
            h[t][7] = acc[t][3].y * inv + b1.w;
            p[t] = h[t][0] * aw0.x + h[t][1] * aw0.y + h[t][2] * aw0.z +
                   h[t][3] * aw0.w + h[t][4] * aw1.x + h[t][5] * aw1.y +
                   h[t][6] * aw1.z + h[t][7] * aw1.w;
        }
#pragma unroll
        for (int off = 1; off < 32; off <<= 1) {
            p[0] += __shfl_xor(p[0], off);
            p[1] += __shfl_xor(p[1], off);
            p[2] += __shfl_xor(p[2], off);
        }
        const float ab = att_b[0];
        const float a0 = p[0] + ab, a1 = p[1] + ab, a2 = p[2] + ab;
        float4 o0, o1;
        o0.x = a0 * h[0][0] + a1 * h[1][0] + a2 * h[2][0];
        o0.y = a0 * h[0][1] + a1 * h[1][1] + a2 * h[2][1];
        o0.z = a0 * h[0][2] + a1 * h[1][2] + a2 * h[2][2];
        o0.w = a0 * h[0][3] + a1 * h[1][3] + a2 * h[2][3];
        o1.x = a0 * h[0][4] + a1 * h[1][4] + a2 * h[2][4];
        o1.y = a0 * h[0][5] + a1 * h[1][5] + a2 * h[2][5];
        o1.z = a0 * h[0][6] + a1 * h[1][6] + a2 * h[2][6];
        o1.w = a0 * h[0][7] + a1 * h[1][7] + a2 * h[2][7];
        *(float4*)(out + (size_t)node * W_OUT + d8 * 8) = o0;
        *(float4*)(out + (size_t)node * W_OUT + d8 * 8 + 4) = o1;
    }
}

// ---------------------------------------------------------------------------
extern "C" void kernel_launch(void* const* d_in, const int* in_sizes, int n_in,
                              void* d_out, int out_size, void* d_ws, size_t ws_size,
                              hipStream_t stream) {
    const float* x     = (const float*)d_in[0];
    const int*   adj   = (const int*)d_in[1];   // [3][2][N_EDGES]
    const float* Ws    = (const float*)d_in[2]; // [3][256][256]
    const float* a_l   = (const float*)d_in[3]; // [3][8][32]
    const float* a_r   = (const float*)d_in[4];
    const float* bias  = (const float*)d_in[5]; // [3][256]
    const float* att_w = (const float*)d_in[6]; // [256]
    const float* att_b = (const float*)d_in[7]; // [1]
    float* out = (float*)d_out;

    // Workspace (~142 MB, no aliasing: gemm now precedes scatter).
    char* w = (char*)d_ws;
    unsigned short* xb = (unsigned short*)w; w += (size_t)N_NODES * W_IN * 2;          // 25.6 MB
    unsigned short* H  = (unsigned short*)w; w += (size_t)NUM_T * N_NODES * W_OUT * 2; // 76.8 MB
    unsigned short* Wt = (unsigned short*)w; w += (size_t)NUM_T * 65536 * 2;           // 0.39 MB
    float* el = (float*)w; w += (size_t)NUM_T * N_NODES * HEADS * 4;   // 4.8 MB
    float* er = (float*)w; w += (size_t)NUM_T * N_NODES * HEADS * 4;   // 4.8 MB
    int* csr_src = (int*)w; w += (size_t)NUM_T * N_EDGES * 4;          // 9.6 MB
    int* row_ptr = (int*)w; w += (size_t)NUM_T * (N_NODES + 1) * 4;    // 0.6 MB
    uint2* part = (uint2*)w; w += (size_t)NUM_T * N_EDGES * 8;         // 19.2 MB
    int* hist_mat = (int*)w; w += (size_t)NUM_T * P1_BLOCKS * NB * 4;  // 0.3 MB
    int* bucket_ptr = (int*)w; w += NUM_T * (NB + 1) * 4;

    // 5 dispatches total (was 13): ~7us per-dispatch tax amortized.
    // 1: converts + per-block histogram (independent block ranges)
    prep<<<PREP_BLOCKS, 256, 0, stream>>>(x, xb, Ws, Wt, adj, hist_mat);
    // 2: hist scan (block 0) || all 3 gemms (blocks 1..)
    scan_gemm<<<SG_BLOCKS, 256, 0, stream>>>(hist_mat, bucket_ptr, xb, Wt, H);
    // 3: bucket scatter (atomic-free placement) || el/er row-scan of H
    scatter_elr<<<SE_BLOCKS, 256, 0, stream>>>(adj, bucket_ptr, hist_mat, part,
                                               H, a_l, a_r, el, er);
    // 4: per-bucket CSR
    p2_csr<<<dim3(NB_USED, NUM_T), 256, 0, stream>>>(part, bucket_ptr, row_ptr,
                                                     csr_src);
    // 5: gather all types + semantic combine
    gat_gather_all<<<GATHER_BLOCKS, 256, 0, stream>>>(
        csr_src, row_ptr, el, er, H, bias, att_w, att_b, out);
}